// Round 1
// baseline (227.205 us; speedup 1.0000x reference)
//
#include <hip/hip_runtime.h>
#include <hip/hip_fp16.h>

#define GT_ROWS 128

typedef _Float16 half2v __attribute__((ext_vector_type(2)));

// ---------------------------------------------------------------- K1: h_raw = x @ W^T, then per-head
// 8x8 W_att transform -> g16 (fp16, packed rows). Zeroes S. Block 0 also computes
// Mt = (W_edge_att @ W_edge)^T, the int64-probe flag, and zeroes sumh.
__global__ __launch_bounds__(256) void g_kernel(
        const float* __restrict__ x, const float* __restrict__ W,
        const float* __restrict__ W_att, const float* __restrict__ W_edge,
        const float* __restrict__ W_edge_att, const int* __restrict__ ei,
        __half* __restrict__ g16, float* __restrict__ S,
        float* __restrict__ Mt, float* __restrict__ sumh, int* __restrict__ flags,
        int N) {
    __shared__ float smem[13056];    // 52.2 KB: sW[64*132] | sx[128*36]; epilogue reuses as 128*68
    float* sW = smem;
    float* sx = smem + 8448;
    int tid = threadIdx.x;
    int nbase = blockIdx.x * GT_ROWS;

    if (blockIdx.x == 0) {           // side jobs for the edge pass
        if (tid < 128) {
            int h = tid >> 4, k = tid & 15;
            float acc = 0.f;
#pragma unroll 8
            for (int j = 0; j < 64; ++j)
                acc += W_edge_att[h * 64 + j] * W_edge[j * 16 + k];
            Mt[k * 8 + h] = acc;     // transposed: Mt[k][h]
        }
        if (tid < 8) sumh[tid] = 0.f;
        if (tid == 0) {
            int zc = 0;              // int64 edge_index: odd int32 words all zero
            for (int i = 1; i < 128; i += 2) zc += (ei[i] == 0);
            flags[0] = (zc >= 60) ? 1 : 0;
        }
    }

    for (int f4 = tid; f4 < 2048; f4 += 256) {          // stage W (same shape G had)
        int l = f4 >> 5, i4 = f4 & 31;
        *(float4*)&sW[l * 132 + i4 * 4] = ((const float4*)W)[f4];
    }
    int lane = tid & 63, wave = tid >> 6;
    int rg = lane >> 3;              // 0..7
    int cg = lane & 7;               // 0..7
    int rbase = wave * 32 + rg;      // block-local rows rbase + 8*r
    float acc[4][8];
#pragma unroll
    for (int r = 0; r < 4; ++r)
#pragma unroll
        for (int c = 0; c < 8; ++c) acc[r][c] = 0.f;

    for (int k0 = 0; k0 < 128; k0 += 32) {
        __syncthreads();
        for (int f4 = tid; f4 < 1024; f4 += 256) {      // stage x K-chunk
            int row = f4 >> 3, i4 = f4 & 7;
            int n = nbase + row;
            float4 v = make_float4(0.f, 0.f, 0.f, 0.f);
            if (n < N) v = *(const float4*)(x + (size_t)n * 128 + k0 + i4 * 4);
            *(float4*)&sx[row * 36 + i4 * 4] = v;
        }
        __syncthreads();
#pragma unroll
        for (int w = 0; w < 8; ++w) {
            float4 gv[8], xv[4];
#pragma unroll
            for (int c = 0; c < 8; ++c)
                gv[c] = *(const float4*)&sW[(cg + 8 * c) * 132 + k0 + w * 4];
#pragma unroll
            for (int r = 0; r < 4; ++r)
                xv[r] = *(const float4*)&sx[(rbase + 8 * r) * 36 + w * 4];
#pragma unroll
            for (int r = 0; r < 4; ++r)
#pragma unroll
                for (int c = 0; c < 8; ++c)
                    acc[r][c] += xv[r].x * gv[c].x + xv[r].y * gv[c].y
                               + xv[r].z * gv[c].z + xv[r].w * gv[c].w;
        }
    }
    // transpose h_raw through LDS (lane cols are stride-8), then W_att transform
    __syncthreads();
#pragma unroll
    for (int r = 0; r < 4; ++r)
#pragma unroll
        for (int c = 0; c < 8; ++c)
            smem[(rbase + 8 * r) * 68 + cg + 8 * c] = acc[r][c];
    __syncthreads();
    {
        float4 wa[16];               // W_att[8][8] in regs (acc is dead now)
#pragma unroll
        for (int q = 0; q < 16; ++q) wa[q] = ((const float4*)W_att)[q];
        int row = tid & 127;
        int n = nbase + row;
        if (n < N) {
#pragma unroll
            for (int j = 0; j < 4; ++j) {
                int q = (tid >> 7) * 4 + j;          // head
                float4 h0 = *(const float4*)&smem[row * 68 + q * 8];
                float4 h1 = *(const float4*)&smem[row * 68 + q * 8 + 4];
                float o[8];
#pragma unroll
                for (int k = 0; k < 8; ++k) {        // g[n,q,k] = <h_raw[n,q,:], W_att[k,:]>
                    float4 w0 = wa[k * 2], w1 = wa[k * 2 + 1];
                    o[k] = h0.x * w0.x + h0.y * w0.y + h0.z * w0.z + h0.w * w0.w
                         + h1.x * w1.x + h1.y * w1.y + h1.z * w1.z + h1.w * w1.w;
                }
                __half2 p0 = __floats2half2_rn(o[0], o[1]);
                __half2 p1 = __floats2half2_rn(o[2], o[3]);
                __half2 p2 = __floats2half2_rn(o[4], o[5]);
                __half2 p3 = __floats2half2_rn(o[6], o[7]);
                uint4 uv = make_uint4(*(unsigned*)&p0, *(unsigned*)&p1,
                                      *(unsigned*)&p2, *(unsigned*)&p3);
                ((uint4*)g16)[(size_t)n * 8 + q] = uv;
            }
        }
    }
    for (int idx = tid; idx < GT_ROWS * 8; idx += 256) { // zero S (ws is poisoned)
        int n = nbase + (idx >> 3);
        if (n < N) S[(size_t)n * 8 + (idx & 7)] = 0.f;
    }
}

// ---------------------------------------------------------------- K2: fused edge pass (R9 form)
// 8-lane group per edge, lane h owns head h.
//  - ei + edge_attr loads are NONTEMPORAL (don't evict g16 from L2)
//  - edge_attr: lane loads only its 8B slice; ea via register-Mt partials +
//    3-step shfl_xor butterfly reduce-scatter (ea[h] lands on lane h). All 8
//    ea values computed up front; main loop is gathers + dot + atomic only.
//  - 4 gather pairs issued before the ea phase so HBM/L2 latency hides under it.
#define EPB 256
__global__ __launch_bounds__(256) void edge_kernel(
        const float* __restrict__ edge_attr, const int* __restrict__ ei,
        const float* __restrict__ Mt, const __half* __restrict__ g16,
        float* __restrict__ S, float* __restrict__ sumh,
        const int* __restrict__ flags, int E) {
    __shared__ float wsum[4][8];
    int tid = threadIdx.x;
    int h = tid & 7;                  // head == lane-in-group
    int grp = tid >> 3;               // 32 groups per block
    int ebase = blockIdx.x * EPB;
    int idx64 = flags[0];

    // ---- preload indices for all 8 edges of this group (nontemporal)
    int sIdx[8], dIdx[8];
    if (idx64) {
        const long long* ei64 = (const long long*)ei;
#pragma unroll
        for (int it = 0; it < 8; ++it) {
            int e = ebase + it * 32 + grp;
            long long sv = 0, dv = 0;
            if (e < E) {
                sv = __builtin_nontemporal_load(ei64 + e);
                dv = __builtin_nontemporal_load(ei64 + (size_t)E + e);
            }
            sIdx[it] = (int)sv;
            dIdx[it] = (int)dv;
        }
    } else {
#pragma unroll
        for (int it = 0; it < 8; ++it) {
            int e = ebase + it * 32 + grp;
            int sv = 0, dv = 0;
            if (e < E) {
                sv = __builtin_nontemporal_load(ei + e);
                dv = __builtin_nontemporal_load(ei + (size_t)E + e);
            }
            sIdx[it] = sv;
            dIdx[it] = dv;
        }
    }

    // ---- per-lane attr slice for all 8 edges (8B each, nontemporal, coalesced
    //      512B per wave per it)
    double araw[8];
#pragma unroll
    for (int it = 0; it < 8; ++it) {
        int e = ebase + it * 32 + grp;
        double a = 0.0;
        if (e < E)
            a = __builtin_nontemporal_load(
                    (const double*)(edge_attr + (size_t)e * 16) + h);
        araw[it] = a;
    }

    // ---- issue first 4 gather pairs; they fly while we do the ea phase
    const uint4* g16v = (const uint4*)g16;
    uint4 gsv[8], gdv[8];
#pragma unroll
    for (int it = 0; it < 4; ++it) {
        gsv[it] = g16v[(size_t)sIdx[it] * 8 + h];
        gdv[it] = g16v[(size_t)dIdx[it] * 8 + h];
    }

    // ---- Mt slice into registers: rows 2h and 2h+1, pre-scaled by D=8
    float mta[8], mtb[8];
    {
        const float4* mr = (const float4*)(Mt + 16 * h);
        float4 m0 = mr[0], m1 = mr[1], m2 = mr[2], m3 = mr[3];
        mta[0] = 8.f * m0.x; mta[1] = 8.f * m0.y; mta[2] = 8.f * m0.z; mta[3] = 8.f * m0.w;
        mta[4] = 8.f * m1.x; mta[5] = 8.f * m1.y; mta[6] = 8.f * m1.z; mta[7] = 8.f * m1.w;
        mtb[0] = 8.f * m2.x; mtb[1] = 8.f * m2.y; mtb[2] = 8.f * m2.z; mtb[3] = 8.f * m2.w;
        mtb[4] = 8.f * m3.x; mtb[5] = 8.f * m3.y; mtb[6] = 8.f * m3.z; mtb[7] = 8.f * m3.w;
    }

    // ---- ea phase: partials + butterfly reduce-scatter (lane l ends with ea[l])
    float ea8[8];
#pragma unroll
    for (int it = 0; it < 8; ++it) {
        double d = araw[it];
        float ax = ((const float*)&d)[0];
        float ay = ((const float*)&d)[1];
        float p[8];
#pragma unroll
        for (int j = 0; j < 8; ++j)
            p[j] = ax * mta[j] + ay * mtb[j];
        // round 1 (xor 4): keep the half matching bit2 of lane
        float q[4];
#pragma unroll
        for (int j = 0; j < 4; ++j) {
            float keep = (h & 4) ? p[4 + j] : p[j];
            float send = (h & 4) ? p[j] : p[4 + j];
            q[j] = keep + __shfl_xor(send, 4, 64);
        }
        // round 2 (xor 2)
        float keep0 = (h & 2) ? q[2] : q[0];
        float send0 = (h & 2) ? q[0] : q[2];
        float r0 = keep0 + __shfl_xor(send0, 2, 64);
        float keep1 = (h & 2) ? q[3] : q[1];
        float send1 = (h & 2) ? q[1] : q[3];
        float r1 = keep1 + __shfl_xor(send1, 2, 64);
        // round 3 (xor 1)
        float keep = (h & 1) ? r1 : r0;
        float send = (h & 1) ? r0 : r1;
        ea8[it] = keep + __shfl_xor(send, 1, 64);   // = 8 * ea[e][h]
    }

    // ---- main loop: depth-4 gather pipeline, dot + exp + atomic
    float wacc = 0.f;
#pragma unroll
    for (int it = 0; it < 8; ++it) {
        if (it + 4 < 8) {                     // gather prefetch, depth 4
            gsv[it + 4] = g16v[(size_t)sIdx[it + 4] * 8 + h];
            gdv[it + 4] = g16v[(size_t)dIdx[it + 4] * 8 + h];
        }
        int e = ebase + it * 32 + grp;
        if (e < E) {
            const half2v* a2 = (const half2v*)&gsv[it];
            const half2v* b2 = (const half2v*)&gdv[it];
            float dot = 0.f;
#if __has_builtin(__builtin_amdgcn_fdot2)
            dot = __builtin_amdgcn_fdot2(a2[0], b2[0], dot, false);
            dot = __builtin_amdgcn_fdot2(a2[1], b2[1], dot, false);
            dot = __builtin_amdgcn_fdot2(a2[2], b2[2], dot, false);
            dot = __builtin_amdgcn_fdot2(a2[3], b2[3], dot, false);
#else
#pragma unroll
            for (int j = 0; j < 4; ++j) {
                float2 fa = __half22float2(*(const __half2*)&a2[j]);
                float2 fb = __half22float2(*(const __half2*)&b2[j]);
                dot += fa.x * fb.x + fa.y * fb.y;
            }
#endif
            float t = dot + ea8[it];                   // ea pre-scaled by D=8
            t = (t > 0.f) ? t : 0.2f * t;              // leaky_relu(0.2)
            float w = __expf(t);
            unsafeAtomicAdd(S + (size_t)dIdx[it] * 8 + h, w);
            wacc += w;
        }
    }
    wacc += __shfl_xor(wacc, 8, 64);
    wacc += __shfl_xor(wacc, 16, 64);
    wacc += __shfl_xor(wacc, 32, 64);
    int wave = tid >> 6, lane = tid & 63;
    if (lane < 8) wsum[wave][lane] = wacc;
    __syncthreads();
    if (tid < 8)
        unsafeAtomicAdd(&sumh[tid], wsum[0][tid] + wsum[1][tid] + wsum[2][tid] + wsum[3][tid]);
}

// ---------------------------------------------------------------- K3: out = relu(((g16 .* S) / sum_h) @ W_out.T)
__global__ __launch_bounds__(256) void out_kernel(
        const __half* __restrict__ g16, const float* __restrict__ S,
        const float* __restrict__ W_out, const float* __restrict__ sumh,
        float* __restrict__ out, int N) {
    __shared__ float sWo[8 * 68];
    __shared__ float sAgg[32 * 68];
    __shared__ float sSum[8];
    int tid = threadIdx.x;
    if (tid < 8) sSum[tid] = sumh[tid];
    __syncthreads();
    for (int idx = tid; idx < 512; idx += 256) {
        int k = idx >> 6, j = idx & 63;
        sWo[k * 68 + j] = W_out[idx] / sSum[j >> 3];   // fold softmax denom
    }
    int nbase = blockIdx.x * 32;
    {   // stage agg = g16 * S: thread -> (row = tid>>3, head = tid&7)
        int row = tid >> 3, q = tid & 7;
        int n = nbase + row;
        float4 v0 = make_float4(0.f, 0.f, 0.f, 0.f), v1 = v0;
        if (n < N) {
            uint4 gv = ((const uint4*)g16)[(size_t)n * 8 + q];
            float sv = S[(size_t)n * 8 + q];
            const __half2* hp = (const __half2*)&gv;
            float2 f0 = __half22float2(hp[0]);
            float2 f1 = __half22float2(hp[1]);
            float2 f2 = __half22float2(hp[2]);
            float2 f3 = __half22float2(hp[3]);
            v0 = make_float4(f0.x * sv, f0.y * sv, f1.x * sv, f1.y * sv);
            v1 = make_float4(f2.x * sv, f2.y * sv, f3.x * sv, f3.y * sv);
        }
        *(float4*)&sAgg[row * 68 + q * 8] = v0;
        *(float4*)&sAgg[row * 68 + q * 8 + 4] = v1;
    }
    __syncthreads();
    int nl = tid >> 3, k = tid & 7;
    int n = nbase + nl;
    float acc = 0.f;
#pragma unroll
    for (int j = 0; j < 64; j += 4) {
        float4 av = *(const float4*)&sAgg[nl * 68 + j];
        float4 wv = *(const float4*)&sWo[k * 68 + j];
        acc += av.x * wv.x + av.y * wv.y + av.z * wv.z + av.w * wv.w;
    }
    if (n < N)
        out[(size_t)n * 8 + k] = (acc > 0.f) ? acc : 0.f;
}

extern "C" void kernel_launch(void* const* d_in, const int* in_sizes, int n_in,
                              void* d_out, int out_size, void* d_ws, size_t ws_size,
                              hipStream_t stream) {
    const float* x          = (const float*)d_in[0];
    const float* edge_attr  = (const float*)d_in[1];
    const float* W          = (const float*)d_in[2];
    const float* W_edge     = (const float*)d_in[3];
    const float* W_edge_att = (const float*)d_in[4];
    const float* W_att      = (const float*)d_in[5];
    const float* W_out      = (const float*)d_in[6];
    const int*   ei         = (const int*)d_in[7];
    float* out = (float*)d_out;

    int N = in_sizes[0] / 128;   // 50000
    int E = in_sizes[1] / 16;    // 800000

    float* ws    = (float*)d_ws;
    float* Mt    = ws;                           // 128
    float* sumh  = ws + 128;                     // 8
    int*   flags = (int*)(ws + 192);             // 1 (own 128B line, away from sumh atomics)
    __half* g16  = (__half*)(ws + 256);          // N*64 fp16 (16B-aligned)
    float* S     = (float*)(g16 + (size_t)N * 64); // N*8 fp32
    // total ~8 MB of ws

    hipLaunchKernelGGL(g_kernel, dim3((N + GT_ROWS - 1) / GT_ROWS), dim3(256), 0, stream,
                       x, W, W_att, W_edge, W_edge_att, ei, g16, S, Mt, sumh, flags, N);
    hipLaunchKernelGGL(edge_kernel, dim3((E + EPB - 1) / EPB), dim3(256), 0, stream,
                       edge_attr, ei, Mt, g16, S, sumh, flags, E);
    hipLaunchKernelGGL(out_kernel, dim3((N + 31) / 32), dim3(256), 0, stream,
                       g16, S, W_out, sumh, out, N);
}